// Round 1
// 1817.673 us; speedup vs baseline: 1.0686x; 1.0686x over previous
//
#include <hip/hip_runtime.h>

// ---------------- problem dims ----------------
#define NBATCH 16
#define NK     1024      // D*D, the contraction dim
#define MMODES 64
#define FOUT   2080      // 64*65/2
#define FPAD   2176      // 17 * 128 (M-dim padding)
#define TILEM  128
#define TILEN  64
#define BK     32

typedef __attribute__((ext_vector_type(8))) short bf16x8;   // 8 bf16 (4 VGPRs)
typedef __attribute__((ext_vector_type(4))) float f32x4;    // 4 fp32 acc
typedef __attribute__((ext_vector_type(4))) unsigned int u32x4;

__device__ __forceinline__ unsigned short f2bf(float f) {
  union { float f; unsigned u; } v; v.f = f;
  unsigned r = v.u + 0x7fffu + ((v.u >> 16) & 1u);   // RNE
  return (unsigned short)(r >> 16);
}

// async global->LDS, 16B per lane; lds dest = wave-uniform base + lane*16
__device__ __forceinline__ void gl2lds16(const unsigned short* g, unsigned short* l) {
  __builtin_amdgcn_global_load_lds((const __attribute__((address_space(1))) void*)g,
                                   (__attribute__((address_space(3))) void*)l, 16, 0, 0);
}

// stage a [rows x 32] bf16 tile (row stride NK) into LDS [rows][32], rows = 64*halves
__device__ __forceinline__ void stage_tile(const unsigned short* gbase, unsigned short* lds,
                                           int tid, int halves) {
  int lane = tid & 63;
  int wv   = tid >> 6;            // 0..3
  int rIn  = lane >> 2;           // 0..15
  int kOfs = (lane & 3) << 3;     // 0,8,16,24 (bf16 elems)
#pragma unroll
  for (int it = 0; it < halves; ++it) {
    int chunk = wv + (it << 2);                    // wave-uniform 1KB chunk id
    int row = (chunk << 4) + rIn;
    gl2lds16(gbase + (size_t)row * NK + kOfs, lds + (chunk << 9));
  }
}

// negate a bf16x8 fragment via sign-bit xor (exact for bf16)
__device__ __forceinline__ bf16x8 negbf8(bf16x8 x) {
  u32x4 t = *(const u32x4*)&x;
  t ^= 0x80008000u;
  return *(const bf16x8*)&t;
}

// ---------------- complex GEMM ----------------
// C[m,n] = sum_k Aop[m,k] * Bop[n,k]   (plain complex product, both K-major)
// accRe = ar*br + ai*(-bi)  (= Re)
// accIm = ar*bi + ai*br     (= Im)
// mode 1: store bf16  Tre = Re, Tim = -Im   (i.e. conj of product)
// mode 2: store float2 {Re, -Im} into out[f*FOUT+g], guarded to f,g < FOUT
__global__ __launch_bounds__(256, 3)
void cgemm(const unsigned short* __restrict__ Are0, const unsigned short* __restrict__ Aim0, long aB,
           const unsigned short* __restrict__ Bre0, const unsigned short* __restrict__ Bim0, long bB,
           unsigned short* Tre0, unsigned short* Tim0, long tB,
           float* out0, long oB, int mode)
{
  __shared__ __align__(16) unsigned short sAre[TILEM * BK];
  __shared__ __align__(16) unsigned short sAim[TILEM * BK];
  __shared__ __align__(16) unsigned short sBre[TILEN * BK];
  __shared__ __align__(16) unsigned short sBim[TILEN * BK];

  const int tid  = threadIdx.x;
  const int z    = blockIdx.z;
  const int bm   = blockIdx.y;
  const int bn   = blockIdx.x;
  const int lane = tid & 63;
  const int wv   = tid >> 6;
  const int wm   = wv >> 1;       // 0..1 : 64-row slab
  const int wn   = wv & 1;        // 0..1 : 32-col slab
  const int quad = lane >> 4;     // 0..3
  const int lcol = lane & 15;

  const unsigned short* Are = Are0 + (size_t)z * aB;
  const unsigned short* Aim = Aim0 + (size_t)z * aB;
  const unsigned short* Bre = Bre0 + (size_t)z * bB;
  const unsigned short* Bim = Bim0 + (size_t)z * bB;

  f32x4 accRe[4][2], accIm[4][2];
#pragma unroll
  for (int mt = 0; mt < 4; ++mt)
#pragma unroll
    for (int nt = 0; nt < 2; ++nt) {
      accRe[mt][nt] = (f32x4){0.f, 0.f, 0.f, 0.f};
      accIm[mt][nt] = (f32x4){0.f, 0.f, 0.f, 0.f};
    }

  const unsigned short* gAre = Are + (size_t)(bm * TILEM) * NK;
  const unsigned short* gAim = Aim + (size_t)(bm * TILEM) * NK;
  const unsigned short* gBre = Bre + (size_t)(bn * TILEN) * NK;
  const unsigned short* gBim = Bim + (size_t)(bn * TILEN) * NK;

  // frag LDS offsets (elements): row*32 + quad*8
  const int aOff = (wm * 64 + lcol) * BK + quad * 8;
  const int bOff = (wn * 32 + lcol) * BK + quad * 8;

  for (int kt = 0; kt < NK / BK; ++kt) {
    __syncthreads();
    const int k0 = kt * BK;
    stage_tile(gAre + k0, sAre, tid, 2);
    stage_tile(gAim + k0, sAim, tid, 2);
    stage_tile(gBre + k0, sBre, tid, 1);
    stage_tile(gBim + k0, sBim, tid, 1);
    __syncthreads();

    bf16x8 ar[4], ai[4], br[2], bi[2], bn_[2];
#pragma unroll
    for (int mt = 0; mt < 4; ++mt) {
      ar[mt] = *(const bf16x8*)(sAre + aOff + mt * 16 * BK);
      ai[mt] = *(const bf16x8*)(sAim + aOff + mt * 16 * BK);
    }
#pragma unroll
    for (int nt = 0; nt < 2; ++nt) {
      br[nt] = *(const bf16x8*)(sBre + bOff + nt * 16 * BK);
      bi[nt] = *(const bf16x8*)(sBim + bOff + nt * 16 * BK);
      bn_[nt] = negbf8(bi[nt]);
    }
#pragma unroll
    for (int mt = 0; mt < 4; ++mt)
#pragma unroll
      for (int nt = 0; nt < 2; ++nt) {
        accRe[mt][nt] = __builtin_amdgcn_mfma_f32_16x16x32_bf16(ar[mt], br[nt],  accRe[mt][nt], 0, 0, 0);
        accRe[mt][nt] = __builtin_amdgcn_mfma_f32_16x16x32_bf16(ai[mt], bn_[nt], accRe[mt][nt], 0, 0, 0);
        accIm[mt][nt] = __builtin_amdgcn_mfma_f32_16x16x32_bf16(ar[mt], bi[nt],  accIm[mt][nt], 0, 0, 0);
        accIm[mt][nt] = __builtin_amdgcn_mfma_f32_16x16x32_bf16(ai[mt], br[nt],  accIm[mt][nt], 0, 0, 0);
      }
  }

  // epilogue — C/D layout: col = lane&15, row = quad*4 + reg
  if (mode == 1) {
    unsigned short* Tre = Tre0 + (size_t)z * tB;
    unsigned short* Tim = Tim0 + (size_t)z * tB;
#pragma unroll
    for (int mt = 0; mt < 4; ++mt)
#pragma unroll
      for (int nt = 0; nt < 2; ++nt) {
        const int col = bn * TILEN + wn * 32 + nt * 16 + lcol;
        const int fb  = bm * TILEM + wm * 64 + mt * 16 + quad * 4;
#pragma unroll
        for (int r = 0; r < 4; ++r) {
          Tre[(size_t)(fb + r) * NK + col] = f2bf(accRe[mt][nt][r]);
          Tim[(size_t)(fb + r) * NK + col] = f2bf(-accIm[mt][nt][r]);
        }
      }
  } else {
    float* out = out0 + (size_t)z * oB;
#pragma unroll
    for (int mt = 0; mt < 4; ++mt)
#pragma unroll
      for (int nt = 0; nt < 2; ++nt) {
        const int g  = bn * TILEN + wn * 32 + nt * 16 + lcol;
        const int fb = bm * TILEM + wm * 64 + mt * 16 + quad * 4;
#pragma unroll
        for (int r = 0; r < 4; ++r) {
          const int f = fb + r;
          if (f < FOUT && g < FOUT) {
            float2 v;
            v.x = accRe[mt][nt][r];
            v.y = -accIm[mt][nt][r];
            *(float2*)(out + ((size_t)f * FOUT + g) * 2) = v;
          }
        }
      }
  }
}

// ---------------- prep: A = u_evolve [FPAD x 1024] bf16, zero-padded ----------------
__global__ void prepA(const float* __restrict__ Ure, const float* __restrict__ Uim,
                      unsigned short* __restrict__ Are, unsigned short* __restrict__ Aim)
{
  const int f  = blockIdx.x;
  const int i0 = threadIdx.x * 4;
  const size_t base = (size_t)f * NK + i0;
  if (f >= FOUT) {
#pragma unroll
    for (int r = 0; r < 4; ++r) { Are[base + r] = 0; Aim[base + r] = 0; }
    return;
  }
  // decode f -> (j,k), np.triu_indices(64) row-major order
  int fr = f, j = 0;
  while (fr >= MMODES - j) { fr -= MMODES - j; ++j; }
  const int k = j + fr;
  const float s = (j == k) ? 0.70710678118654752f : 1.0f;
  const int x = i0 >> 5;                       // same x for all 4 elems
  const float ujxr = Ure[j * MMODES + x], ujxi = Uim[j * MMODES + x];
  const float ukxr = Ure[k * MMODES + x], ukxi = Uim[k * MMODES + x];
#pragma unroll
  for (int r = 0; r < 4; ++r) {
    const int y = (i0 + r) & 31;
    const float ukyr = Ure[k * MMODES + 32 + y], ukyi = Uim[k * MMODES + 32 + y];
    const float ujyr = Ure[j * MMODES + 32 + y], ujyi = Uim[j * MMODES + 32 + y];
    float re = ujxr * ukyr - ujxi * ukyi + ukxr * ujyr - ukxi * ujyi;
    float im = ujxr * ukyi + ujxi * ukyr + ukxr * ujyi + ukxi * ujyr;
    Are[base + r] = f2bf(s * re);
    Aim[base + r] = f2bf(s * im);
  }
}

// ---------------- prep: Ht[j][i] = H[i][j], bf16, per batch ----------------
// H[i,j] = rho[i,j] (i<j) ; conj(rho[j,i]) (i>j) ; Re(rho[i,i]) (diag)
__global__ void prepH(const float* __restrict__ rho_re, const float* __restrict__ rho_im,
                      unsigned short* __restrict__ Htre, unsigned short* __restrict__ Htim, int b0)
{
  const int z = blockIdx.z;
  const size_t rbase = (size_t)(b0 + z) * NK * NK;
  const int lin = blockIdx.x * blockDim.x + threadIdx.x;   // j*1024 + i
  const int j = lin >> 10, i = lin & 1023;
  const int lo = min(i, j), hi = max(i, j);
  const size_t src = rbase + (size_t)lo * NK + hi;
  const float re = rho_re[src];
  const float im = (i < j) ? rho_im[src] : (i > j) ? -rho_im[src] : 0.f;
  const size_t o = (size_t)z * NK * NK + lin;
  Htre[o] = f2bf(re);
  Htim[o] = f2bf(im);
}

// ---------------- launch ----------------
extern "C" void kernel_launch(void* const* d_in, const int* in_sizes, int n_in,
                              void* d_out, int out_size, void* d_ws, size_t ws_size,
                              hipStream_t stream) {
  const float* rho_re = (const float*)d_in[0];
  const float* rho_im = (const float*)d_in[1];
  const float* U_re   = (const float*)d_in[2];
  const float* U_im   = (const float*)d_in[3];
  float* out = (float*)d_out;

  // workspace layout (bytes):  A planes | Ht (2 batches) | T (2 batches)
  char* ws = (char*)d_ws;
  const size_t szA = (size_t)FPAD * NK * 2;        // 4,456,448 per plane
  unsigned short* Are  = (unsigned short*)(ws);
  unsigned short* Aim  = (unsigned short*)(ws + szA);
  const size_t oHt = 2 * szA;
  const size_t szH = (size_t)2 * NK * NK * 2;      // 2 batches per plane
  unsigned short* Htre = (unsigned short*)(ws + oHt);
  unsigned short* Htim = (unsigned short*)(ws + oHt + szH);
  const size_t oT = oHt + 2 * szH;
  const size_t szT = (size_t)2 * FPAD * NK * 2;    // 2 batches per plane
  unsigned short* Tre  = (unsigned short*)(ws + oT);
  unsigned short* Tim  = (unsigned short*)(ws + oT + szT);
  // total ws use: ~33.5 MB

  prepA<<<dim3(FPAD, 1, 1), dim3(256), 0, stream>>>(U_re, U_im, Are, Aim);

  for (int p = 0; p < 8; ++p) {
    prepH<<<dim3(4096, 1, 2), dim3(256), 0, stream>>>(rho_re, rho_im, Htre, Htim, p * 2);
    // T' = conj(A · H): M=FPAD rows of A, N=1024 cols (rows of Ht), K=1024
    cgemm<<<dim3(16, 17, 2), dim3(256), 0, stream>>>(
        Are, Aim, 0L, Htre, Htim, (long)NK * NK,
        Tre, Tim, (long)FPAD * NK, (float*)nullptr, 0L, 1);
    // out = conj(T' · A): M=FPAD rows of T', N=2112 cols (rows of A), K=1024
    cgemm<<<dim3(33, 17, 2), dim3(256), 0, stream>>>(
        Tre, Tim, (long)FPAD * NK, Are, Aim, 0L,
        (unsigned short*)nullptr, (unsigned short*)nullptr, 0L,
        out + (size_t)p * 2 * FOUT * FOUT * 2, (long)FOUT * FOUT * 2, 2);
  }
}

// Round 3
// 1608.346 us; speedup vs baseline: 1.2077x; 1.1302x over previous
//
#include <hip/hip_runtime.h>

// ---------------- problem dims ----------------
#define NBATCH 16
#define NK     1024      // D*D, the contraction dim
#define MMODES 64
#define FOUT   2080      // 64*65/2
#define FPAD   2176      // 17 * 128 (M-dim padding)
#define TILEM  128
#define TILEN  64
#define BK     32

typedef __attribute__((ext_vector_type(8))) short bf16x8;   // 8 bf16 (4 VGPRs)
typedef __attribute__((ext_vector_type(4))) float f32x4;    // 4 fp32 acc
typedef __attribute__((ext_vector_type(4))) unsigned int u32x4;

__device__ __forceinline__ unsigned short f2bf(float f) {
  union { float f; unsigned u; } v; v.f = f;
  unsigned r = v.u + 0x7fffu + ((v.u >> 16) & 1u);   // RNE
  return (unsigned short)(r >> 16);
}

// async global->LDS, 16B per lane; lds dest = wave-uniform base + lane*16
__device__ __forceinline__ void gl2lds16(const unsigned short* g, unsigned short* l) {
  __builtin_amdgcn_global_load_lds((const __attribute__((address_space(1))) void*)g,
                                   (__attribute__((address_space(3))) void*)l, 16, 0, 0);
}

// stage a [rows x 32] bf16 tile (row stride NK) into LDS [rows][32], rows = 64*halves
__device__ __forceinline__ void stage_tile(const unsigned short* gbase, unsigned short* lds,
                                           int tid, int halves) {
  int lane = tid & 63;
  int wv   = tid >> 6;            // 0..3
  int rIn  = lane >> 2;           // 0..15
  int kOfs = (lane & 3) << 3;     // 0,8,16,24 (bf16 elems)
#pragma unroll
  for (int it = 0; it < halves; ++it) {
    int chunk = wv + (it << 2);                    // wave-uniform 1KB chunk id
    int row = (chunk << 4) + rIn;
    gl2lds16(gbase + (size_t)row * NK + kOfs, lds + (chunk << 9));
  }
}

// negate a bf16x8 fragment via sign-bit xor (exact for bf16)
__device__ __forceinline__ bf16x8 negbf8(bf16x8 x) {
  u32x4 t = *(const u32x4*)&x;
  t ^= 0x80008000u;
  return *(const bf16x8*)&t;
}

// ---------------- complex GEMM ----------------
// C[m,n] = sum_k Aop[m,k] * Bop[n,k]   (plain complex product, both K-major)
// accRe = ar*br + ai*(-bi)  (= Re)
// accIm = ar*bi + ai*br     (= Im)
// mode 1: store bf16  Tre = Re, Tim = -Im   (i.e. conj of product)
// mode 2: store float2 {Re, -Im} into out[f*FOUT+g], guarded to f,g < FOUT.
//         Output is Hermitian: tiles strictly below the diagonal (bn < 2*bm)
//         are skipped; a separate hermitize pass mirrors conj(upper) -> lower.
__global__ __launch_bounds__(256, 3)
void cgemm(const unsigned short* __restrict__ Are0, const unsigned short* __restrict__ Aim0, long aB,
           const unsigned short* __restrict__ Bre0, const unsigned short* __restrict__ Bim0, long bB,
           unsigned short* Tre0, unsigned short* Tim0, long tB,
           float* out0, long oB, int mode)
{
  __shared__ __align__(16) unsigned short sAre[TILEM * BK];
  __shared__ __align__(16) unsigned short sAim[TILEM * BK];
  __shared__ __align__(16) unsigned short sBre[TILEN * BK];
  __shared__ __align__(16) unsigned short sBim[TILEN * BK];

  const int tid  = threadIdx.x;
  const int z    = blockIdx.z;
  const int bm   = blockIdx.y;
  const int bn   = blockIdx.x;

  // Hermitian-output tile skip: tile covers f in [128bm,128bm+127], g in [64bn,64bn+63].
  // Skip iff every element has f > g  <=>  128bm > 64bn+63  <=>  bn < 2bm.
  if (mode == 2 && bn < 2 * bm) return;

  const int lane = tid & 63;
  const int wv   = tid >> 6;
  const int wm   = wv >> 1;       // 0..1 : 64-row slab
  const int wn   = wv & 1;        // 0..1 : 32-col slab
  const int quad = lane >> 4;     // 0..3
  const int lcol = lane & 15;

  const unsigned short* Are = Are0 + (size_t)z * aB;
  const unsigned short* Aim = Aim0 + (size_t)z * aB;
  const unsigned short* Bre = Bre0 + (size_t)z * bB;
  const unsigned short* Bim = Bim0 + (size_t)z * bB;

  f32x4 accRe[4][2], accIm[4][2];
#pragma unroll
  for (int mt = 0; mt < 4; ++mt)
#pragma unroll
    for (int nt = 0; nt < 2; ++nt) {
      accRe[mt][nt] = (f32x4){0.f, 0.f, 0.f, 0.f};
      accIm[mt][nt] = (f32x4){0.f, 0.f, 0.f, 0.f};
    }

  const unsigned short* gAre = Are + (size_t)(bm * TILEM) * NK;
  const unsigned short* gAim = Aim + (size_t)(bm * TILEM) * NK;
  const unsigned short* gBre = Bre + (size_t)(bn * TILEN) * NK;
  const unsigned short* gBim = Bim + (size_t)(bn * TILEN) * NK;

  // frag LDS offsets (elements): row*32 + quad*8
  const int aOff = (wm * 64 + lcol) * BK + quad * 8;
  const int bOff = (wn * 32 + lcol) * BK + quad * 8;

  for (int kt = 0; kt < NK / BK; ++kt) {
    __syncthreads();
    const int k0 = kt * BK;
    stage_tile(gAre + k0, sAre, tid, 2);
    stage_tile(gAim + k0, sAim, tid, 2);
    stage_tile(gBre + k0, sBre, tid, 1);
    stage_tile(gBim + k0, sBim, tid, 1);
    __syncthreads();

    bf16x8 ar[4], ai[4], br[2], bi[2], bn_[2];
#pragma unroll
    for (int mt = 0; mt < 4; ++mt) {
      ar[mt] = *(const bf16x8*)(sAre + aOff + mt * 16 * BK);
      ai[mt] = *(const bf16x8*)(sAim + aOff + mt * 16 * BK);
    }
#pragma unroll
    for (int nt = 0; nt < 2; ++nt) {
      br[nt] = *(const bf16x8*)(sBre + bOff + nt * 16 * BK);
      bi[nt] = *(const bf16x8*)(sBim + bOff + nt * 16 * BK);
      bn_[nt] = negbf8(bi[nt]);
    }
#pragma unroll
    for (int mt = 0; mt < 4; ++mt)
#pragma unroll
      for (int nt = 0; nt < 2; ++nt) {
        accRe[mt][nt] = __builtin_amdgcn_mfma_f32_16x16x32_bf16(ar[mt], br[nt],  accRe[mt][nt], 0, 0, 0);
        accRe[mt][nt] = __builtin_amdgcn_mfma_f32_16x16x32_bf16(ai[mt], bn_[nt], accRe[mt][nt], 0, 0, 0);
        accIm[mt][nt] = __builtin_amdgcn_mfma_f32_16x16x32_bf16(ar[mt], bi[nt],  accIm[mt][nt], 0, 0, 0);
        accIm[mt][nt] = __builtin_amdgcn_mfma_f32_16x16x32_bf16(ai[mt], br[nt],  accIm[mt][nt], 0, 0, 0);
      }
  }

  // epilogue — C/D layout: col = lane&15, row = quad*4 + reg
  if (mode == 1) {
    unsigned short* Tre = Tre0 + (size_t)z * tB;
    unsigned short* Tim = Tim0 + (size_t)z * tB;
#pragma unroll
    for (int mt = 0; mt < 4; ++mt)
#pragma unroll
      for (int nt = 0; nt < 2; ++nt) {
        const int col = bn * TILEN + wn * 32 + nt * 16 + lcol;
        const int fb  = bm * TILEM + wm * 64 + mt * 16 + quad * 4;
#pragma unroll
        for (int r = 0; r < 4; ++r) {
          Tre[(size_t)(fb + r) * NK + col] = f2bf(accRe[mt][nt][r]);
          Tim[(size_t)(fb + r) * NK + col] = f2bf(-accIm[mt][nt][r]);
        }
      }
  } else {
    float* out = out0 + (size_t)z * oB;
#pragma unroll
    for (int mt = 0; mt < 4; ++mt)
#pragma unroll
      for (int nt = 0; nt < 2; ++nt) {
        const int g  = bn * TILEN + wn * 32 + nt * 16 + lcol;
        const int fb = bm * TILEM + wm * 64 + mt * 16 + quad * 4;
#pragma unroll
        for (int r = 0; r < 4; ++r) {
          const int f = fb + r;
          if (f < FOUT && g < FOUT) {
            float2 v;
            v.x = accRe[mt][nt][r];
            v.y = -accIm[mt][nt][r];
            *(float2*)(out + ((size_t)f * FOUT + g) * 2) = v;
          }
        }
      }
  }
}

// ---------------- hermitize: lower := conj(upper^T), tiled transpose ----------------
// out layout: [FOUT][FOUT] float2 per batch.  2080 = 65 * 32 exactly.
// Tiles (tr, tc) with tc <= tr: read 32x32 at rows f=tc*32.., cols g=tr*32..
// (upper side), LDS-transpose, write conj to rows g=tr*32.., cols f=tc*32..
#define HT 32
#define NTILE 65
__global__ __launch_bounds__(256)
void hermitize(float* __restrict__ out0)
{
  __shared__ float2 ld[HT][HT + 1];
  const int tid = threadIdx.x;
  const int t = blockIdx.x;
  // decode t -> (tr, tc), tc <= tr, t = tr*(tr+1)/2 + tc  (integer-hardened)
  int tr = (int)((sqrtf(8.f * (float)t + 1.f) - 1.f) * 0.5f);
  if (tr < 0) tr = 0;
  if (tr > NTILE - 1) tr = NTILE - 1;
  while (tr + 1 <= NTILE - 1 && (tr + 1) * (tr + 2) / 2 <= t) ++tr;
  while (tr > 0 && tr * (tr + 1) / 2 > t) --tr;
  const int tc = t - tr * (tr + 1) / 2;

  float* out = out0 + (size_t)blockIdx.z * FOUT * FOUT * 2;

  // read phase: coalesced rows of the upper tile
  const int gj = tid & 31;          // g offset within tr-tile
  const int i4 = (tid >> 5) << 2;   // f offset base
#pragma unroll
  for (int r = 0; r < 4; ++r) {
    const int fi = i4 + r;
    const int f = tc * HT + fi;
    const int g = tr * HT + gj;
    float2 v = *(const float2*)(out + ((size_t)f * FOUT + g) * 2);
    ld[gj][fi] = v;                 // transposed store
  }
  __syncthreads();

  // write phase: coalesced rows of the lower tile (conjugate)
  const int fi2 = tid & 31;         // f offset within tc-tile
  const int j4 = (tid >> 5) << 2;   // g offset base
#pragma unroll
  for (int r = 0; r < 4; ++r) {
    const int j = j4 + r;
    if (tr == tc && j <= fi2) continue;   // strictly-lower only on diag tiles
    float2 v = ld[j][fi2];
    v.y = -v.y;
    const int grow = tr * HT + j;
    const int fcol = tc * HT + fi2;
    *(float2*)(out + ((size_t)grow * FOUT + fcol) * 2) = v;
  }
}

// ---------------- prep: A = u_evolve [FPAD x 1024] bf16, zero-padded ----------------
__global__ void prepA(const float* __restrict__ Ure, const float* __restrict__ Uim,
                      unsigned short* __restrict__ Are, unsigned short* __restrict__ Aim)
{
  const int f  = blockIdx.x;
  const int i0 = threadIdx.x * 4;
  const size_t base = (size_t)f * NK + i0;
  if (f >= FOUT) {
#pragma unroll
    for (int r = 0; r < 4; ++r) { Are[base + r] = 0; Aim[base + r] = 0; }
    return;
  }
  // decode f -> (j,k), np.triu_indices(64) row-major order
  int fr = f, j = 0;
  while (fr >= MMODES - j) { fr -= MMODES - j; ++j; }
  const int k = j + fr;
  const float s = (j == k) ? 0.70710678118654752f : 1.0f;
  const int x = i0 >> 5;                       // same x for all 4 elems
  const float ujxr = Ure[j * MMODES + x], ujxi = Uim[j * MMODES + x];
  const float ukxr = Ure[k * MMODES + x], ukxi = Uim[k * MMODES + x];
#pragma unroll
  for (int r = 0; r < 4; ++r) {
    const int y = (i0 + r) & 31;
    const float ukyr = Ure[k * MMODES + 32 + y], ukyi = Uim[k * MMODES + 32 + y];
    const float ujyr = Ure[j * MMODES + 32 + y], ujyi = Uim[j * MMODES + 32 + y];
    float re = ujxr * ukyr - ujxi * ukyi + ukxr * ujyr - ukxi * ujyi;
    float im = ujxr * ukyi + ujxi * ukyr + ukxr * ujyi + ukxi * ujyr;
    Are[base + r] = f2bf(s * re);
    Aim[base + r] = f2bf(s * im);
  }
}

// ---------------- prep: Ht[j][i] = H[i][j], bf16, per batch ----------------
// H[i,j] = rho[i,j] (i<j) ; conj(rho[j,i]) (i>j) ; Re(rho[i,i]) (diag)
__global__ void prepH(const float* __restrict__ rho_re, const float* __restrict__ rho_im,
                      unsigned short* __restrict__ Htre, unsigned short* __restrict__ Htim, int b0)
{
  const int z = blockIdx.z;
  const size_t rbase = (size_t)(b0 + z) * NK * NK;
  const int lin = blockIdx.x * blockDim.x + threadIdx.x;   // j*1024 + i
  const int j = lin >> 10, i = lin & 1023;
  const int lo = min(i, j), hi = max(i, j);
  const size_t src = rbase + (size_t)lo * NK + hi;
  const float re = rho_re[src];
  const float im = (i < j) ? rho_im[src] : (i > j) ? -rho_im[src] : 0.f;
  const size_t o = (size_t)z * NK * NK + lin;
  Htre[o] = f2bf(re);
  Htim[o] = f2bf(im);
}

// ---------------- launch ----------------
extern "C" void kernel_launch(void* const* d_in, const int* in_sizes, int n_in,
                              void* d_out, int out_size, void* d_ws, size_t ws_size,
                              hipStream_t stream) {
  const float* rho_re = (const float*)d_in[0];
  const float* rho_im = (const float*)d_in[1];
  const float* U_re   = (const float*)d_in[2];
  const float* U_im   = (const float*)d_in[3];
  float* out = (float*)d_out;

  // workspace layout (bytes):  A planes | Ht (2 batches) | T (2 batches)
  char* ws = (char*)d_ws;
  const size_t szA = (size_t)FPAD * NK * 2;        // 4,456,448 per plane
  unsigned short* Are  = (unsigned short*)(ws);
  unsigned short* Aim  = (unsigned short*)(ws + szA);
  const size_t oHt = 2 * szA;
  const size_t szH = (size_t)2 * NK * NK * 2;      // 2 batches per plane
  unsigned short* Htre = (unsigned short*)(ws + oHt);
  unsigned short* Htim = (unsigned short*)(ws + oHt + szH);
  const size_t oT = oHt + 2 * szH;
  const size_t szT = (size_t)2 * FPAD * NK * 2;    // 2 batches per plane
  unsigned short* Tre  = (unsigned short*)(ws + oT);
  unsigned short* Tim  = (unsigned short*)(ws + oT + szT);
  // total ws use: ~33.5 MB

  prepA<<<dim3(FPAD, 1, 1), dim3(256), 0, stream>>>(U_re, U_im, Are, Aim);

  for (int p = 0; p < 8; ++p) {
    prepH<<<dim3(4096, 1, 2), dim3(256), 0, stream>>>(rho_re, rho_im, Htre, Htim, p * 2);
    // T' = conj(A · H): M=FPAD rows of A, N=1024 cols (rows of Ht), K=1024
    cgemm<<<dim3(16, 17, 2), dim3(256), 0, stream>>>(
        Are, Aim, 0L, Htre, Htim, (long)NK * NK,
        Tre, Tim, (long)FPAD * NK, (float*)nullptr, 0L, 1);
    // out = conj(T' · A): M=FPAD rows of T', N=2112 cols (rows of A), K=1024
    // upper-triangular tiles only (bn >= 2*bm); lower filled by hermitize
    cgemm<<<dim3(33, 17, 2), dim3(256), 0, stream>>>(
        Tre, Tim, (long)FPAD * NK, Are, Aim, 0L,
        (unsigned short*)nullptr, (unsigned short*)nullptr, 0L,
        out + (size_t)p * 2 * FOUT * FOUT * 2, (long)FOUT * FOUT * 2, 2);
  }

  // mirror conj(upper) -> strict lower for all 16 batches
  hermitize<<<dim3(NTILE * (NTILE + 1) / 2, 1, NBATCH), dim3(256), 0, stream>>>(out);
}